// Round 4
// baseline (692.509 us; speedup 1.0000x reference)
//
#include <hip/hip_runtime.h>

#define N_NODES 100000
#define N_EDGES 3200000
#define NUM_FEATURES 128
#define DIM 10
#define NUM_GRAPHS 64

#define BSHIFT 8                             // 256 nodes per bucket
#define BSIZE (1 << BSHIFT)
#define NB ((N_NODES + BSIZE - 1) / BSIZE)   // 391 buckets
#define CHUNKS 2                             // spmm blocks per bucket
#define EPB 8192                             // edges per block in hist/place
#define EBLOCKS ((N_EDGES + EPB - 1) / EPB)  // 391
#define ACC_STRIDE 11                        // LDS pad: gcd(11,32)=1 -> no bank hotspots
#define TILE (BSIZE * DIM)                   // 2560 floats per bucket tile

// ---------------------------------------------------------------------------
// Kernel A: h1 = features @ W1   [100000,128] x [128,10]
// ---------------------------------------------------------------------------
__global__ __launch_bounds__(256) void k_gemm_w1(const float* __restrict__ feat,
                                                 const float* __restrict__ W1,
                                                 float* __restrict__ h1) {
    int gid  = blockIdx.x * blockDim.x + threadIdx.x;
    int node = gid >> 5;
    int lane = gid & 31;
    if (node >= N_NODES) return;

    float w[4][DIM];
#pragma unroll
    for (int j = 0; j < 4; ++j)
#pragma unroll
        for (int k = 0; k < DIM; ++k)
            w[j][k] = W1[(lane * 4 + j) * DIM + k];

    const float4 f = *reinterpret_cast<const float4*>(feat + (size_t)node * NUM_FEATURES + lane * 4);
    float fv[4] = {f.x, f.y, f.z, f.w};

    float acc[DIM];
#pragma unroll
    for (int k = 0; k < DIM; ++k) acc[k] = 0.f;
#pragma unroll
    for (int j = 0; j < 4; ++j)
#pragma unroll
        for (int k = 0; k < DIM; ++k)
            acc[k] += fv[j] * w[j][k];

#pragma unroll
    for (int off = 16; off > 0; off >>= 1)
#pragma unroll
        for (int k = 0; k < DIM; ++k)
            acc[k] += __shfl_xor(acc[k], off);

    if (lane == 0) {
#pragma unroll
        for (int k = 0; k < DIM; ++k) h1[node * DIM + k] = acc[k];
    }
}

// ---------------------------------------------------------------------------
// Bucket histogram (LDS) -> one global atomic per (block,bin)
// ---------------------------------------------------------------------------
__global__ __launch_bounds__(512) void k_bhist(const int* __restrict__ dst,
                                               int* __restrict__ bcnt) {
    __shared__ int h[NB];
    for (int t = threadIdx.x; t < NB; t += 512) h[t] = 0;
    __syncthreads();
    int base = blockIdx.x * EPB;
    int end  = min(base + EPB, N_EDGES);
    for (int i = base + threadIdx.x; i < end; i += 512)
        atomicAdd(&h[dst[i] >> BSHIFT], 1);
    __syncthreads();
    for (int t = threadIdx.x; t < NB; t += 512)
        if (h[t]) atomicAdd(&bcnt[t], h[t]);
}

__global__ void k_bscan(const int* __restrict__ bcnt,
                        int* __restrict__ bstart,
                        int* __restrict__ cursor) {
    if (threadIdx.x == 0) {
        int run = 0;
        for (int b = 0; b < NB; ++b) {
            bstart[b] = run;
            cursor[b] = run;
            run += bcnt[b];
        }
        bstart[NB] = run;
    }
}

// ---------------------------------------------------------------------------
// Bucket placement: packed edge word (dst&255)<<17 | src
// ---------------------------------------------------------------------------
__global__ __launch_bounds__(512) void k_bplace(const int* __restrict__ src,
                                                const int* __restrict__ dst,
                                                int* __restrict__ cursor,
                                                int* __restrict__ pk) {
    __shared__ int h[NB];
    for (int t = threadIdx.x; t < NB; t += 512) h[t] = 0;
    __syncthreads();
    int base = blockIdx.x * EPB;
    int end  = min(base + EPB, N_EDGES);
    for (int i = base + threadIdx.x; i < end; i += 512)
        atomicAdd(&h[dst[i] >> BSHIFT], 1);
    __syncthreads();
    for (int t = threadIdx.x; t < NB; t += 512) {
        int c = h[t];
        h[t] = c ? atomicAdd(&cursor[t], c) : 0;
    }
    __syncthreads();
    for (int i = base + threadIdx.x; i < end; i += 512) {
        int d   = dst[i];
        int s   = src[i];
        int bin = d >> BSHIFT;
        int pos = atomicAdd(&h[bin], 1);
        pk[pos] = ((d & (BSIZE - 1)) << 17) | s;
    }
}

// ---------------------------------------------------------------------------
// Bucketed SpMM, chunked: grid = NB*CHUNKS blocks; each block owns a private
// LDS tile (stride-11 padded), processes its chunk of the bucket's edge list
// with a 4x-unrolled slot loop (24 outstanding gathers/wave), then writes the
// partial tile coalesced. k_merge sums the CHUNKS partials.
// ---------------------------------------------------------------------------
template <int RELU>
__global__ __launch_bounds__(512) void k_spmm(const float* __restrict__ h,
                                              const int* __restrict__ bstart,
                                              const int* __restrict__ pk,
                                              float* __restrict__ part) {
    __shared__ float acc[BSIZE * ACC_STRIDE];
    for (int t = threadIdx.x; t < BSIZE * ACC_STRIDE; t += 512) acc[t] = 0.f;
    __syncthreads();

    int b     = blockIdx.x / CHUNKS;
    int chunk = blockIdx.x % CHUNKS;
    int s0 = bstart[b];
    int len = bstart[b + 1] - s0;
    int c0 = s0 + (len * chunk) / CHUNKS;
    int c1 = s0 + (len * (chunk + 1)) / CHUNKS;

    int wave = threadIdx.x >> 6;
    int lane = threadIdx.x & 63;
    int slot = lane / 10;          // 0..6 (6 = idle lanes 60..63)
    int k    = lane - slot * 10;

    if (slot < 6) {
        const int stride = 48;     // 8 waves * 6 slots
        int e = c0 + wave * 6 + slot;
        for (; e + 3 * stride < c1; e += 4 * stride) {
            int p0 = pk[e];
            int p1 = pk[e + stride];
            int p2 = pk[e + 2 * stride];
            int p3 = pk[e + 3 * stride];
            float v0 = h[(size_t)(p0 & 0x1FFFF) * DIM + k];
            float v1 = h[(size_t)(p1 & 0x1FFFF) * DIM + k];
            float v2 = h[(size_t)(p2 & 0x1FFFF) * DIM + k];
            float v3 = h[(size_t)(p3 & 0x1FFFF) * DIM + k];
            if (RELU) {
                v0 = fmaxf(v0, 0.f); v1 = fmaxf(v1, 0.f);
                v2 = fmaxf(v2, 0.f); v3 = fmaxf(v3, 0.f);
            }
            atomicAdd(&acc[(p0 >> 17) * ACC_STRIDE + k], v0);
            atomicAdd(&acc[(p1 >> 17) * ACC_STRIDE + k], v1);
            atomicAdd(&acc[(p2 >> 17) * ACC_STRIDE + k], v2);
            atomicAdd(&acc[(p3 >> 17) * ACC_STRIDE + k], v3);
        }
        for (; e < c1; e += stride) {
            int   p = pk[e];
            float v = h[(size_t)(p & 0x1FFFF) * DIM + k];
            if (RELU) v = fmaxf(v, 0.f);
            atomicAdd(&acc[(p >> 17) * ACC_STRIDE + k], v);
        }
    }
    __syncthreads();

    float* pb = part + (size_t)blockIdx.x * TILE;
    for (int t = threadIdx.x; t < TILE; t += 512)
        pb[t] = acc[(t / DIM) * ACC_STRIDE + t % DIM];
}

// sum the CHUNKS partial tiles -> outp (coalesced both sides)
__global__ __launch_bounds__(256) void k_merge(const float* __restrict__ part,
                                               float* __restrict__ outp) {
    int b     = blockIdx.x;
    int nbase = b << BSHIFT;
    const float* p0 = part + (size_t)(b * CHUNKS) * TILE;
    for (int t = threadIdx.x; t < TILE; t += 256) {
        float s = 0.f;
#pragma unroll
        for (int c = 0; c < CHUNKS; ++c) s += p0[c * TILE + t];
        int node = nbase + t / DIM;
        if (node < N_NODES) outp[(size_t)node * DIM + t % DIM] = s;
    }
}

// ---------------------------------------------------------------------------
// Per-graph sums + counts (graph_ids sorted -> wave-uniform fast path)
// ---------------------------------------------------------------------------
__global__ __launch_bounds__(256) void k_pool(const float* __restrict__ agg2,
                                              const int* __restrict__ gids,
                                              float* __restrict__ sums,
                                              float* __restrict__ cnt) {
    int n      = blockIdx.x * blockDim.x + threadIdx.x;
    bool valid = (n < N_NODES);
    int g      = valid ? gids[n] : -1;

    float v[DIM];
#pragma unroll
    for (int k = 0; k < DIM; ++k)
        v[k] = valid ? agg2[(size_t)n * DIM + k] : 0.f;

    int  g0  = __shfl(g, 0);
    bool uni = __all(g == g0);

    if (uni && g0 >= 0) {
#pragma unroll
        for (int off = 32; off > 0; off >>= 1)
#pragma unroll
            for (int k = 0; k < DIM; ++k)
                v[k] += __shfl_xor(v[k], off);
        if ((threadIdx.x & 63) == 0) {
#pragma unroll
            for (int k = 0; k < DIM; ++k) atomicAdd(&sums[g0 * DIM + k], v[k]);
            atomicAdd(&cnt[g0], 64.f);
        }
    } else if (valid) {
#pragma unroll
        for (int k = 0; k < DIM; ++k) atomicAdd(&sums[g * DIM + k], v[k]);
        atomicAdd(&cnt[g], 1.f);
    }
}

__global__ void k_final(const float* __restrict__ sums, const float* __restrict__ cnt,
                        const float* __restrict__ W2, const float* __restrict__ W3,
                        float* __restrict__ out) {
    int g = threadIdx.x;
    if (g >= NUM_GRAPHS) return;
    float c = fmaxf(cnt[g], 1.f);
    float p[DIM];
#pragma unroll
    for (int k = 0; k < DIM; ++k) p[k] = sums[g * DIM + k] / c;
    float z = 0.f;
#pragma unroll
    for (int j = 0; j < DIM; ++j) {
        float t = 0.f;
#pragma unroll
        for (int k = 0; k < DIM; ++k) t += p[k] * W2[k * DIM + j];
        z += t * W3[j];
    }
    out[g] = 1.f / (1.f + expf(-z));
}

// ---------------------------------------------------------------------------
// Workspace layout (bytes):
//   buf0 (h1, later agg2) [0,         4000000)
//   agg1                  [4000000,   8000000)
//   pk                    [8000000,  20800000)   3.2M packed edges
//   part                  [20800000, 28807680)   782 x 2560 f32 (reused both passes)
//   bcnt                  [28807680, 28809280)   391 int (pad)   <- zeroed
//   sums                  [28809280, 28811840)   64x10 f32       <- zeroed
//   cnt                   [28811840, 28812096)   64 f32          <- zeroed
//   bstart                [28812096, 28813664)   392 int
//   cursor                [28813664, 28815232)   391 int
// ---------------------------------------------------------------------------
extern "C" void kernel_launch(void* const* d_in, const int* in_sizes, int n_in,
                              void* d_out, int out_size, void* d_ws, size_t ws_size,
                              hipStream_t stream) {
    const float* feat = (const float*)d_in[0];
    const float* W1   = (const float*)d_in[1];
    const float* W2   = (const float*)d_in[2];
    const float* W3   = (const float*)d_in[3];
    const int*   src  = (const int*)d_in[4];
    const int*   dst  = (const int*)d_in[5];
    const int*   gids = (const int*)d_in[6];
    float*       out  = (float*)d_out;

    char* ws = (char*)d_ws;
    float* buf0   = (float*)(ws);              // h1, then agg2
    float* agg1   = (float*)(ws + 4000000);
    int*   pk     = (int*)(ws + 8000000);
    float* part   = (float*)(ws + 20800000);
    int*   bcnt   = (int*)(ws + 28807680);
    float* sums   = (float*)(ws + 28809280);
    float* cnt    = (float*)(ws + 28811840);
    int*   bstart = (int*)(ws + 28812096);
    int*   cursor = (int*)(ws + 28813664);

    hipMemsetAsync(ws + 28807680, 0, 4416, stream);  // bcnt + sums + cnt

    k_gemm_w1<<<(N_NODES * 32 + 255) / 256, 256, 0, stream>>>(feat, W1, buf0);
    k_bhist <<<EBLOCKS, 512, 0, stream>>>(dst, bcnt);
    k_bscan <<<1, 64, 0, stream>>>(bcnt, bstart, cursor);
    k_bplace<<<EBLOCKS, 512, 0, stream>>>(src, dst, cursor, pk);

    k_spmm<0><<<NB * CHUNKS, 512, 0, stream>>>(buf0, bstart, pk, part);
    k_merge  <<<NB, 256, 0, stream>>>(part, agg1);
    k_spmm<1><<<NB * CHUNKS, 512, 0, stream>>>(agg1, bstart, pk, part);
    k_merge  <<<NB, 256, 0, stream>>>(part, buf0);      // buf0 = agg2 now

    k_pool <<<(N_NODES + 255) / 256, 256, 0, stream>>>(buf0, gids, sums, cnt);
    k_final<<<1, 64, 0, stream>>>(sums, cnt, W2, W3, out);
}

// Round 5
// 653.008 us; speedup vs baseline: 1.0605x; 1.0605x over previous
//
#include <hip/hip_runtime.h>

#define N_NODES 100000
#define N_EDGES 3200000
#define NUM_FEATURES 128
#define DIM 10
#define NUM_GRAPHS 64

#define BSHIFT 8                             // 256 nodes per bucket
#define BSIZE (1 << BSHIFT)
#define NB ((N_NODES + BSIZE - 1) / BSIZE)   // 391 buckets
#define CHUNKS 2                             // spmm1 blocks per bucket
#define EPB 8192                             // edges per block in hist/place
#define EBLOCKS ((N_EDGES + EPB - 1) / EPB)  // 391
#define ACC_STRIDE 11                        // LDS pad: gcd(11,32)=1
#define TILE (BSIZE * DIM)                   // 2560 floats per bucket tile
#define HSTRIDE 16                           // h1 row stride (64B-aligned gathers)

// ---------------------------------------------------------------------------
// Kernel A: h1 = features @ W1, output padded to stride 16
// ---------------------------------------------------------------------------
__global__ __launch_bounds__(256) void k_gemm_w1(const float* __restrict__ feat,
                                                 const float* __restrict__ W1,
                                                 float* __restrict__ h1) {
    int gid  = blockIdx.x * blockDim.x + threadIdx.x;
    int node = gid >> 5;
    int lane = gid & 31;
    if (node >= N_NODES) return;

    float w[4][DIM];
#pragma unroll
    for (int j = 0; j < 4; ++j)
#pragma unroll
        for (int k = 0; k < DIM; ++k)
            w[j][k] = W1[(lane * 4 + j) * DIM + k];

    const float4 f = *reinterpret_cast<const float4*>(feat + (size_t)node * NUM_FEATURES + lane * 4);
    float fv[4] = {f.x, f.y, f.z, f.w};

    float acc[DIM];
#pragma unroll
    for (int k = 0; k < DIM; ++k) acc[k] = 0.f;
#pragma unroll
    for (int j = 0; j < 4; ++j)
#pragma unroll
        for (int k = 0; k < DIM; ++k)
            acc[k] += fv[j] * w[j][k];

#pragma unroll
    for (int off = 16; off > 0; off >>= 1)
#pragma unroll
        for (int k = 0; k < DIM; ++k)
            acc[k] += __shfl_xor(acc[k], off);

    if (lane == 0) {
#pragma unroll
        for (int k = 0; k < DIM; ++k) h1[(size_t)node * HSTRIDE + k] = acc[k];
    }
}

// ---------------------------------------------------------------------------
// Graph boundaries from sorted gids: bound[g] = first node with gid >= g,
// bound[64] = N.  (handles empty graphs)
// ---------------------------------------------------------------------------
__global__ __launch_bounds__(256) void k_bounds(const int* __restrict__ gids,
                                                int* __restrict__ bound) {
    int n = blockIdx.x * blockDim.x + threadIdx.x;
    if (n >= N_NODES) return;
    int g  = gids[n];
    int gp = n ? gids[n - 1] : -1;
    for (int v = gp + 1; v <= g; ++v) bound[v] = n;
    if (n == N_NODES - 1)
        for (int v = g + 1; v <= NUM_GRAPHS; ++v) bound[v] = N_NODES;
}

// ---------------------------------------------------------------------------
// Dual histogram (dst buckets + src buckets), LDS-first
// ---------------------------------------------------------------------------
__global__ __launch_bounds__(512) void k_bhist(const int* __restrict__ src,
                                               const int* __restrict__ dst,
                                               int* __restrict__ bcnt,
                                               int* __restrict__ bcnt2) {
    __shared__ int hd[NB], hs[NB];
    for (int t = threadIdx.x; t < NB; t += 512) { hd[t] = 0; hs[t] = 0; }
    __syncthreads();
    int base = blockIdx.x * EPB;
    int end  = min(base + EPB, N_EDGES);
    for (int i = base + threadIdx.x; i < end; i += 512) {
        atomicAdd(&hd[dst[i] >> BSHIFT], 1);
        atomicAdd(&hs[src[i] >> BSHIFT], 1);
    }
    __syncthreads();
    for (int t = threadIdx.x; t < NB; t += 512) {
        if (hd[t]) atomicAdd(&bcnt[t], hd[t]);
        if (hs[t]) atomicAdd(&bcnt2[t], hs[t]);
    }
}

// ---------------------------------------------------------------------------
// Parallel exclusive scans of both 391-bin histograms (one block)
// ---------------------------------------------------------------------------
__global__ __launch_bounds__(512) void k_bscan(const int* __restrict__ bcnt,
                                               const int* __restrict__ bcnt2,
                                               int* __restrict__ bstart,
                                               int* __restrict__ b2start,
                                               int* __restrict__ cursor,
                                               int* __restrict__ cursor2) {
    __shared__ int ld[512];
    int t = threadIdx.x;
#pragma unroll
    for (int pass = 0; pass < 2; ++pass) {
        const int* in = pass ? bcnt2 : bcnt;
        int x = (t < NB) ? in[t] : 0;
        ld[t] = x;
        __syncthreads();
        for (int off = 1; off < 512; off <<= 1) {
            int v = (t >= off) ? ld[t - off] : 0;
            __syncthreads();
            ld[t] += v;
            __syncthreads();
        }
        int excl = t ? ld[t - 1] : 0;
        if (t < NB) {
            if (pass) { b2start[t] = excl; cursor2[t] = excl; }
            else      { bstart[t]  = excl; cursor[t]  = excl; }
        }
        if (t == NB - 1) {
            if (pass) b2start[NB] = ld[t];
            else      bstart[NB]  = ld[t];
        }
        __syncthreads();
    }
}

// ---------------------------------------------------------------------------
// Dual placement:
//   pk  (dst-bucketed, int):    (dst&255)<<17 | src      -> pass 1
//   pk2 (src-bucketed, ushort): gid(dst)<<8 | (src&255)  -> pass 2
// gid(dst) via 6-step binary search over the 65 graph boundaries (LDS).
// ---------------------------------------------------------------------------
__global__ __launch_bounds__(512) void k_bplace(const int* __restrict__ src,
                                                const int* __restrict__ dst,
                                                const int* __restrict__ bound,
                                                int* __restrict__ cursor,
                                                int* __restrict__ cursor2,
                                                int* __restrict__ pk,
                                                unsigned short* __restrict__ pk2) {
    __shared__ int hd[NB], hs[NB];
    __shared__ int bnd[NUM_GRAPHS + 1];
    for (int t = threadIdx.x; t < NB; t += 512) { hd[t] = 0; hs[t] = 0; }
    if (threadIdx.x < NUM_GRAPHS + 1) bnd[threadIdx.x] = bound[threadIdx.x];
    __syncthreads();
    int base = blockIdx.x * EPB;
    int end  = min(base + EPB, N_EDGES);
    for (int i = base + threadIdx.x; i < end; i += 512) {
        atomicAdd(&hd[dst[i] >> BSHIFT], 1);
        atomicAdd(&hs[src[i] >> BSHIFT], 1);
    }
    __syncthreads();
    for (int t = threadIdx.x; t < NB; t += 512) {
        int c = hd[t]; hd[t] = c ? atomicAdd(&cursor[t],  c) : 0;
        int d = hs[t]; hs[t] = d ? atomicAdd(&cursor2[t], d) : 0;
    }
    __syncthreads();
    for (int i = base + threadIdx.x; i < end; i += 512) {
        int d = dst[i];
        int s = src[i];
        int posd = atomicAdd(&hd[d >> BSHIFT], 1);
        pk[posd] = ((d & (BSIZE - 1)) << 17) | s;
        // gid = max g with bnd[g] <= d
        int lo = 0, hi = NUM_GRAPHS - 1;
#pragma unroll
        for (int it = 0; it < 6; ++it) {
            int mid = (lo + hi + 1) >> 1;
            if (bnd[mid] <= d) lo = mid; else hi = mid - 1;
        }
        int poss = atomicAdd(&hs[s >> BSHIFT], 1);
        pk2[poss] = (unsigned short)((lo << BSHIFT) | (s & (BSIZE - 1)));
    }
}

// ---------------------------------------------------------------------------
// Pass 1 SpMM (dst-bucketed, chunked): 8-deep pipelined random gather of
// h1[src] (64B-aligned rows), LDS tile accumulate, coalesced partial write.
// ---------------------------------------------------------------------------
__global__ __launch_bounds__(512) void k_spmm1(const float* __restrict__ h,
                                               const int* __restrict__ bstart,
                                               const int* __restrict__ pk,
                                               float* __restrict__ part) {
    __shared__ float acc[BSIZE * ACC_STRIDE];
    for (int t = threadIdx.x; t < BSIZE * ACC_STRIDE; t += 512) acc[t] = 0.f;
    __syncthreads();

    int b     = blockIdx.x / CHUNKS;
    int chunk = blockIdx.x % CHUNKS;
    int s0  = bstart[b];
    int len = bstart[b + 1] - s0;
    int c0  = s0 + (len * chunk) / CHUNKS;
    int c1  = s0 + (len * (chunk + 1)) / CHUNKS;

    int wave = threadIdx.x >> 6;
    int lane = threadIdx.x & 63;
    int slot = lane / 10;          // 0..6 (6 = idle lanes 60..63)
    int k    = lane - slot * 10;

    if (slot < 6) {
        const int STR = 48;        // 8 waves * 6 slots
        int e = c0 + wave * 6 + slot;
        for (; e + 7 * STR < c1; e += 8 * STR) {
            int p[8];
            float v[8];
#pragma unroll
            for (int u = 0; u < 8; ++u) p[u] = pk[e + u * STR];
#pragma unroll
            for (int u = 0; u < 8; ++u)
                v[u] = h[(size_t)(p[u] & 0x1FFFF) * HSTRIDE + k];
#pragma unroll
            for (int u = 0; u < 8; ++u)
                atomicAdd(&acc[(p[u] >> 17) * ACC_STRIDE + k], v[u]);
        }
        for (; e < c1; e += STR) {
            int   p = pk[e];
            float v = h[(size_t)(p & 0x1FFFF) * HSTRIDE + k];
            atomicAdd(&acc[(p >> 17) * ACC_STRIDE + k], v);
        }
    }
    __syncthreads();

    float* pb = part + (size_t)blockIdx.x * TILE;
    for (int t = threadIdx.x; t < TILE; t += 512)
        pb[t] = acc[(t / DIM) * ACC_STRIDE + t % DIM];
}

// merge CHUNKS partials + fused relu -> r  (stride DIM)
__global__ __launch_bounds__(256) void k_merge_relu(const float* __restrict__ part,
                                                    float* __restrict__ r) {
    int b     = blockIdx.x;
    int nbase = b << BSHIFT;
    const float* p0 = part + (size_t)(b * CHUNKS) * TILE;
    for (int t = threadIdx.x; t < TILE; t += 256) {
        float s = 0.f;
#pragma unroll
        for (int c = 0; c < CHUNKS; ++c) s += p0[c * TILE + t];
        int node = nbase + t / DIM;
        if (node < N_NODES) r[(size_t)node * DIM + t % DIM] = fmaxf(s, 0.f);
    }
}

// ---------------------------------------------------------------------------
// Pass 2 (src-bucketed): sums[g] += sum over edges of r[src] with g=gid(dst).
// r-tile coalesced into LDS; edges are 2B; all per-edge work is LDS-local.
// ---------------------------------------------------------------------------
__global__ __launch_bounds__(512) void k_pass2(const float* __restrict__ r,
                                               const int* __restrict__ b2start,
                                               const unsigned short* __restrict__ pk2,
                                               float* __restrict__ sums) {
    __shared__ float tile[BSIZE * ACC_STRIDE];
    __shared__ float acc[NUM_GRAPHS * ACC_STRIDE];
    int b     = blockIdx.x;
    int nbase = b << BSHIFT;
    for (int t = threadIdx.x; t < TILE; t += 512) {
        int node = nbase + t / DIM;
        tile[(t / DIM) * ACC_STRIDE + t % DIM] =
            (node < N_NODES) ? r[(size_t)node * DIM + t % DIM] : 0.f;
    }
    for (int t = threadIdx.x; t < NUM_GRAPHS * ACC_STRIDE; t += 512) acc[t] = 0.f;
    __syncthreads();

    int e0 = b2start[b];
    int e1 = b2start[b + 1];
    for (int e = e0 + threadIdx.x; e < e1; e += 512) {
        int p   = pk2[e];
        int loc = p & (BSIZE - 1);
        int g   = p >> BSHIFT;
#pragma unroll
        for (int k = 0; k < DIM; ++k)
            atomicAdd(&acc[g * ACC_STRIDE + k], tile[loc * ACC_STRIDE + k]);
    }
    __syncthreads();
    for (int t = threadIdx.x; t < NUM_GRAPHS * DIM; t += 512) {
        float v = acc[(t / DIM) * ACC_STRIDE + t % DIM];
        if (v != 0.f) atomicAdd(&sums[t], v);
    }
}

// out[g] = sigmoid(((sums[g]/max(cnt,1)) @ W2) @ W3), cnt from boundaries
__global__ void k_final(const float* __restrict__ sums, const int* __restrict__ bound,
                        const float* __restrict__ W2, const float* __restrict__ W3,
                        float* __restrict__ out) {
    int g = threadIdx.x;
    if (g >= NUM_GRAPHS) return;
    float c = fmaxf((float)(bound[g + 1] - bound[g]), 1.f);
    float p[DIM];
#pragma unroll
    for (int k = 0; k < DIM; ++k) p[k] = sums[g * DIM + k] / c;
    float z = 0.f;
#pragma unroll
    for (int j = 0; j < DIM; ++j) {
        float t = 0.f;
#pragma unroll
        for (int k = 0; k < DIM; ++k) t += p[k] * W2[k * DIM + j];
        z += t * W3[j];
    }
    out[g] = 1.f / (1.f + expf(-z));
}

// ---------------------------------------------------------------------------
// Workspace (bytes):
//   h1       [0,         6400000)   100k x 16 f32 (padded rows)
//   pk       [6400000,  19200000)   3.2M int (dst-bucketed); r aliases its
//                                   first 4 MB after spmm1 completes
//   pk2      [19200000, 25600000)   3.2M ushort (src-bucketed)
//   part     [25600000, 33607680)   782 x 2560 f32
//   bcnt     [33607680, +1600)      <- zeroed
//   bcnt2    [33609280, +1600)      <- zeroed
//   sums     [33610880, +2560)      <- zeroed
//   bstart   [33613440, +1600)
//   b2start  [33615040, +1600)
//   cursor   [33616640, +1600)
//   cursor2  [33618240, +1600)
//   bound    [33619840, +260)
// ---------------------------------------------------------------------------
extern "C" void kernel_launch(void* const* d_in, const int* in_sizes, int n_in,
                              void* d_out, int out_size, void* d_ws, size_t ws_size,
                              hipStream_t stream) {
    const float* feat = (const float*)d_in[0];
    const float* W1   = (const float*)d_in[1];
    const float* W2   = (const float*)d_in[2];
    const float* W3   = (const float*)d_in[3];
    const int*   src  = (const int*)d_in[4];
    const int*   dst  = (const int*)d_in[5];
    const int*   gids = (const int*)d_in[6];
    float*       out  = (float*)d_out;

    char* ws = (char*)d_ws;
    float*          h1      = (float*)(ws);
    int*            pk      = (int*)(ws + 6400000);
    float*          r       = (float*)(ws + 6400000);       // aliases pk (dead after spmm1)
    unsigned short* pk2     = (unsigned short*)(ws + 19200000);
    float*          part    = (float*)(ws + 25600000);
    int*            bcnt    = (int*)(ws + 33607680);
    int*            bcnt2   = (int*)(ws + 33609280);
    float*          sums    = (float*)(ws + 33610880);
    int*            bstart  = (int*)(ws + 33613440);
    int*            b2start = (int*)(ws + 33615040);
    int*            cursor  = (int*)(ws + 33616640);
    int*            cursor2 = (int*)(ws + 33618240);
    int*            bound   = (int*)(ws + 33619840);

    hipMemsetAsync(ws + 33607680, 0, 5760, stream);   // bcnt + bcnt2 + sums

    k_gemm_w1<<<(N_NODES * 32 + 255) / 256, 256, 0, stream>>>(feat, W1, h1);
    k_bounds <<<(N_NODES + 255) / 256, 256, 0, stream>>>(gids, bound);
    k_bhist  <<<EBLOCKS, 512, 0, stream>>>(src, dst, bcnt, bcnt2);
    k_bscan  <<<1, 512, 0, stream>>>(bcnt, bcnt2, bstart, b2start, cursor, cursor2);
    k_bplace <<<EBLOCKS, 512, 0, stream>>>(src, dst, bound, cursor, cursor2, pk, pk2);

    k_spmm1     <<<NB * CHUNKS, 512, 0, stream>>>(h1, bstart, pk, part);
    k_merge_relu<<<NB, 256, 0, stream>>>(part, r);
    k_pass2     <<<NB, 512, 0, stream>>>(r, b2start, pk2, sums);

    k_final<<<1, 64, 0, stream>>>(sums, bound, W2, W3, out);
}

// Round 6
// 317.101 us; speedup vs baseline: 2.1839x; 2.0593x over previous
//
#include <hip/hip_runtime.h>

#define N_NODES 100000
#define N_EDGES 3200000
#define NUM_FEATURES 128
#define DIM 10
#define NUM_GRAPHS 64

#define BSHIFT 8                             // 256 nodes per bucket
#define BSIZE (1 << BSHIFT)
#define NB ((N_NODES + BSIZE - 1) / BSIZE)   // 391 buckets
#define CHUNKS 2                             // chunks per bucket (both passes)
#define EPB 8192                             // edges per block in hist/place
#define EBLOCKS ((N_EDGES + EPB - 1) / EPB)  // 391
#define TILE (BSIZE * DIM)                   // 2560 floats per bucket tile
#define HSTRIDE 16                           // h1 row stride (64B-aligned gathers)
#define CAP 4608                             // max edges per spmm1 chunk (6-sigma safe)
#define NCHUNK (NB * CHUNKS)                 // 782

// ---------------------------------------------------------------------------
// Kernel A: h1 = features @ W1, output padded to stride 16
// ---------------------------------------------------------------------------
__global__ __launch_bounds__(256) void k_gemm_w1(const float* __restrict__ feat,
                                                 const float* __restrict__ W1,
                                                 float* __restrict__ h1) {
    int gid  = blockIdx.x * blockDim.x + threadIdx.x;
    int node = gid >> 5;
    int lane = gid & 31;
    if (node >= N_NODES) return;

    float w[4][DIM];
#pragma unroll
    for (int j = 0; j < 4; ++j)
#pragma unroll
        for (int k = 0; k < DIM; ++k)
            w[j][k] = W1[(lane * 4 + j) * DIM + k];

    const float4 f = *reinterpret_cast<const float4*>(feat + (size_t)node * NUM_FEATURES + lane * 4);
    float fv[4] = {f.x, f.y, f.z, f.w};

    float acc[DIM];
#pragma unroll
    for (int k = 0; k < DIM; ++k) acc[k] = 0.f;
#pragma unroll
    for (int j = 0; j < 4; ++j)
#pragma unroll
        for (int k = 0; k < DIM; ++k)
            acc[k] += fv[j] * w[j][k];

#pragma unroll
    for (int off = 16; off > 0; off >>= 1)
#pragma unroll
        for (int k = 0; k < DIM; ++k)
            acc[k] += __shfl_xor(acc[k], off);

    if (lane == 0) {
#pragma unroll
        for (int k = 0; k < DIM; ++k) h1[(size_t)node * HSTRIDE + k] = acc[k];
    }
}

// ---------------------------------------------------------------------------
// Graph boundaries from sorted gids
// ---------------------------------------------------------------------------
__global__ __launch_bounds__(256) void k_bounds(const int* __restrict__ gids,
                                                int* __restrict__ bound) {
    int n = blockIdx.x * blockDim.x + threadIdx.x;
    if (n >= N_NODES) return;
    int g  = gids[n];
    int gp = n ? gids[n - 1] : -1;
    for (int v = gp + 1; v <= g; ++v) bound[v] = n;
    if (n == N_NODES - 1)
        for (int v = g + 1; v <= NUM_GRAPHS; ++v) bound[v] = N_NODES;
}

// ---------------------------------------------------------------------------
// Dual histogram (dst buckets + src buckets)
// ---------------------------------------------------------------------------
__global__ __launch_bounds__(512) void k_bhist(const int* __restrict__ src,
                                               const int* __restrict__ dst,
                                               int* __restrict__ bcnt,
                                               int* __restrict__ bcnt2) {
    __shared__ int hd[NB], hs[NB];
    for (int t = threadIdx.x; t < NB; t += 512) { hd[t] = 0; hs[t] = 0; }
    __syncthreads();
    int base = blockIdx.x * EPB;
    int end  = min(base + EPB, N_EDGES);
    for (int i = base + threadIdx.x; i < end; i += 512) {
        atomicAdd(&hd[dst[i] >> BSHIFT], 1);
        atomicAdd(&hs[src[i] >> BSHIFT], 1);
    }
    __syncthreads();
    for (int t = threadIdx.x; t < NB; t += 512) {
        if (hd[t]) atomicAdd(&bcnt[t], hd[t]);
        if (hs[t]) atomicAdd(&bcnt2[t], hs[t]);
    }
}

// ---------------------------------------------------------------------------
// Parallel exclusive scans of both 391-bin histograms
// ---------------------------------------------------------------------------
__global__ __launch_bounds__(512) void k_bscan(const int* __restrict__ bcnt,
                                               const int* __restrict__ bcnt2,
                                               int* __restrict__ bstart,
                                               int* __restrict__ b2start,
                                               int* __restrict__ cursor,
                                               int* __restrict__ cursor2) {
    __shared__ int ld[512];
    int t = threadIdx.x;
#pragma unroll
    for (int pass = 0; pass < 2; ++pass) {
        const int* in = pass ? bcnt2 : bcnt;
        int x = (t < NB) ? in[t] : 0;
        ld[t] = x;
        __syncthreads();
        for (int off = 1; off < 512; off <<= 1) {
            int v = (t >= off) ? ld[t - off] : 0;
            __syncthreads();
            ld[t] += v;
            __syncthreads();
        }
        int excl = t ? ld[t - 1] : 0;
        if (t < NB) {
            if (pass) { b2start[t] = excl; cursor2[t] = excl; }
            else      { bstart[t]  = excl; cursor[t]  = excl; }
        }
        if (t == NB - 1) {
            if (pass) b2start[NB] = ld[t];
            else      bstart[NB]  = ld[t];
        }
        __syncthreads();
    }
}

// ---------------------------------------------------------------------------
// Dual placement: pk (dst-bucketed): (dst&255)<<17|src ; pk2 (src-bucketed):
// gid(dst)<<8|(src&255), gid via binary search over graph boundaries.
// ---------------------------------------------------------------------------
__global__ __launch_bounds__(512) void k_bplace(const int* __restrict__ src,
                                                const int* __restrict__ dst,
                                                const int* __restrict__ bound,
                                                int* __restrict__ cursor,
                                                int* __restrict__ cursor2,
                                                int* __restrict__ pk,
                                                unsigned short* __restrict__ pk2) {
    __shared__ int hd[NB], hs[NB];
    __shared__ int bnd[NUM_GRAPHS + 1];
    for (int t = threadIdx.x; t < NB; t += 512) { hd[t] = 0; hs[t] = 0; }
    if (threadIdx.x < NUM_GRAPHS + 1) bnd[threadIdx.x] = bound[threadIdx.x];
    __syncthreads();
    int base = blockIdx.x * EPB;
    int end  = min(base + EPB, N_EDGES);
    for (int i = base + threadIdx.x; i < end; i += 512) {
        atomicAdd(&hd[dst[i] >> BSHIFT], 1);
        atomicAdd(&hs[src[i] >> BSHIFT], 1);
    }
    __syncthreads();
    for (int t = threadIdx.x; t < NB; t += 512) {
        int c = hd[t]; hd[t] = c ? atomicAdd(&cursor[t],  c) : 0;
        int d = hs[t]; hs[t] = d ? atomicAdd(&cursor2[t], d) : 0;
    }
    __syncthreads();
    for (int i = base + threadIdx.x; i < end; i += 512) {
        int d = dst[i];
        int s = src[i];
        int posd = atomicAdd(&hd[d >> BSHIFT], 1);
        pk[posd] = ((d & (BSIZE - 1)) << 17) | s;
        int lo = 0, hi = NUM_GRAPHS - 1;
#pragma unroll
        for (int it = 0; it < 6; ++it) {
            int mid = (lo + hi + 1) >> 1;
            if (bnd[mid] <= d) lo = mid; else hi = mid - 1;
        }
        int poss = atomicAdd(&hs[s >> BSHIFT], 1);
        pk2[poss] = (unsigned short)((lo << BSHIFT) | (s & (BSIZE - 1)));
    }
}

// ---------------------------------------------------------------------------
// Pass 1 SpMM v3: in-block counting sort to exact dst-loc (2 int atomics per
// edge), then exclusive-owner segmented gather with register accumulation —
// ZERO per-edge f32 atomics. Partial tile written compact to `part`.
// ---------------------------------------------------------------------------
__global__ __launch_bounds__(512) void k_spmm1(const float* __restrict__ h,
                                               const int* __restrict__ bstart,
                                               const int* __restrict__ pk,
                                               float* __restrict__ part) {
    __shared__ int eh[CAP];
    __shared__ int srt[CAP];
    __shared__ int hist[BSIZE];
    __shared__ int cur[BSIZE];

    int b     = blockIdx.x / CHUNKS;
    int chunk = blockIdx.x % CHUNKS;
    int s0  = bstart[b];
    int len = bstart[b + 1] - s0;
    int c0  = s0 + (len * chunk) / CHUNKS;
    int c1  = s0 + (len * (chunk + 1)) / CHUNKS;
    int n   = c1 - c0;
    int nc  = min(n, CAP);

    for (int t = threadIdx.x; t < BSIZE; t += 512) hist[t] = 0;
    __syncthreads();

    // phase 1: stash + histogram (1 int atomic / edge)
    for (int i = threadIdx.x; i < nc; i += 512) {
        int p = pk[c0 + i];
        eh[i] = p;
        atomicAdd(&hist[p >> 17], 1);
    }
    __syncthreads();

    // phase 2: exclusive scan (wave 0)
    if (threadIdx.x < 64) {
        int l = threadIdx.x;
        int carry = 0;
#pragma unroll
        for (int j = 0; j < 4; ++j) {
            int x = hist[j * 64 + l];
            int v = x;
#pragma unroll
            for (int off = 1; off < 64; off <<= 1) {
                int t2 = __shfl_up(v, off);
                if (l >= off) v += t2;
            }
            cur[j * 64 + l] = carry + v - x;
            carry += __shfl(v, 63);
        }
    }
    __syncthreads();

    // phase 3: scatter into sorted order (1 int atomic / edge)
    for (int i = threadIdx.x; i < nc; i += 512) {
        int p = eh[i];
        int pos = atomicAdd(&cur[p >> 17], 1);
        srt[pos] = p;
    }
    __syncthreads();
    // post-scatter: cur[loc] = end of loc's span; start = loc ? cur[loc-1] : 0

    // phase 4: segmented gather, register acc, exclusive non-atomic writes
    int wave = threadIdx.x >> 6;
    int lane = threadIdx.x & 63;
    int grp  = lane / 10;          // 0..6 (6 = idle lanes 60..63)
    int k    = lane - grp * 10;
    float* pb = part + (size_t)blockIdx.x * TILE;

    if (grp < 6) {
        int g48 = wave * 6 + grp;  // 0..47
        for (int loc = g48; loc < BSIZE; loc += 48) {
            int e0 = loc ? cur[loc - 1] : 0;
            int e1 = cur[loc];
            float a0 = 0.f, a1 = 0.f;
            int e = e0;
            for (; e + 1 < e1; e += 2) {
                int p0 = srt[e], p1 = srt[e + 1];
                a0 += h[(size_t)(p0 & 0x1FFFF) * HSTRIDE + k];
                a1 += h[(size_t)(p1 & 0x1FFFF) * HSTRIDE + k];
            }
            if (e < e1) a0 += h[(size_t)(srt[e] & 0x1FFFF) * HSTRIDE + k];
            pb[loc * DIM + k] = a0 + a1;
        }
    }
    __syncthreads();

    // overflow fallback (statistically never; correctness guard)
    for (int i = CAP + threadIdx.x; i < n; i += 512) {
        int p = pk[c0 + i];
        int loc = p >> 17, s = p & 0x1FFFF;
#pragma unroll
        for (int kk = 0; kk < DIM; ++kk)
            atomicAdd(&pb[loc * DIM + kk], h[(size_t)s * HSTRIDE + kk]);
    }
}

// merge CHUNKS partials + fused relu -> r  (stride DIM)
__global__ __launch_bounds__(256) void k_merge_relu(const float* __restrict__ part,
                                                    float* __restrict__ r) {
    int b     = blockIdx.x;
    int nbase = b << BSHIFT;
    const float* p0 = part + (size_t)(b * CHUNKS) * TILE;
    for (int t = threadIdx.x; t < TILE; t += 256) {
        float s = 0.f;
#pragma unroll
        for (int c = 0; c < CHUNKS; ++c) s += p0[c * TILE + t];
        int node = nbase + t / DIM;
        if (node < N_NODES) r[(size_t)node * DIM + t % DIM] = fmaxf(s, 0.f);
    }
}

// ---------------------------------------------------------------------------
// Pass 2 v2 (count-matrix): per src-bucket chunk, build C[loc][g] counts in
// LDS (1 packed int atomic / edge; 2x16-bit fields), then atomic-free
// reduction: sums_partial[g][k] = sum_loc C[loc][g] * r[loc][k] with r rows
// in registers (lane=g, shfl broadcast). Partials -> part2.
// ---------------------------------------------------------------------------
__global__ __launch_bounds__(512) void k_pass2(const float* __restrict__ r,
                                               const int* __restrict__ b2start,
                                               const unsigned short* __restrict__ pk2,
                                               float* __restrict__ part2) {
    __shared__ unsigned int cnt[BSIZE * 32];          // 32 KB: [loc][g>>1], 2x16-bit
    __shared__ float wacc[8 * NUM_GRAPHS * DIM];      // 20 KB per-wave partials

    int b     = blockIdx.x / CHUNKS;
    int chunk = blockIdx.x % CHUNKS;
    int nbase = b << BSHIFT;
    int wave  = threadIdx.x >> 6;
    int lane  = threadIdx.x & 63;

    for (int t = threadIdx.x; t < BSIZE * 32; t += 512) cnt[t] = 0u;

    // preload r rows: lane l (<32) of wave w holds row nbase + w + 8*l
    float rreg[DIM];
#pragma unroll
    for (int k = 0; k < DIM; ++k) rreg[k] = 0.f;
    if (lane < 32) {
        int node = nbase + wave + 8 * lane;
        if (node < N_NODES) {
            const float2* rp = (const float2*)(r + (size_t)node * DIM);
#pragma unroll
            for (int j = 0; j < 5; ++j) {
                float2 t2 = rp[j];
                rreg[2 * j] = t2.x; rreg[2 * j + 1] = t2.y;
            }
        }
    }
    __syncthreads();

    int e0  = b2start[b];
    int len = b2start[b + 1] - e0;
    int c0  = e0 + (len * chunk) / CHUNKS;
    int c1  = e0 + (len * (chunk + 1)) / CHUNKS;
    for (int e = c0 + threadIdx.x; e < c1; e += 512) {
        int p   = pk2[e];
        int loc = p & (BSIZE - 1);
        int g   = p >> BSHIFT;
        atomicAdd(&cnt[loc * 32 + (g >> 1)], 1u << ((g & 1) * 16));
    }
    __syncthreads();

    // reduction: lane = g; wave w covers locs w, w+8, ..., w+248
    float acc[DIM];
#pragma unroll
    for (int k = 0; k < DIM; ++k) acc[k] = 0.f;
    int sh = (lane & 1) * 16;
    for (int i = 0; i < 32; ++i) {
        int loc = wave + 8 * i;
        unsigned int w32 = cnt[loc * 32 + (lane >> 1)];   // conflict-free, pair-broadcast
        float cf = (float)((w32 >> sh) & 0xFFFFu);
#pragma unroll
        for (int k = 0; k < DIM; ++k)
            acc[k] += cf * __shfl(rreg[k], i);            // broadcast row loc
    }
#pragma unroll
    for (int k = 0; k < DIM; ++k)
        wacc[wave * (NUM_GRAPHS * DIM) + lane * DIM + k] = acc[k];
    __syncthreads();

    float* po = part2 + (size_t)blockIdx.x * (NUM_GRAPHS * DIM);
    for (int t = threadIdx.x; t < NUM_GRAPHS * DIM; t += 512) {
        float s = 0.f;
#pragma unroll
        for (int w = 0; w < 8; ++w) s += wacc[w * (NUM_GRAPHS * DIM) + t];
        po[t] = s;
    }
}

// sum 782 chunk partials -> sums (global atomics, 6400 total; sums pre-zeroed)
__global__ __launch_bounds__(640) void k_sums(const float* __restrict__ part2,
                                              float* __restrict__ sums) {
    int t  = threadIdx.x;                 // 0..639 = g*10+k
    int b0 = blockIdx.x * 79;
    int b1 = min(b0 + 79, NCHUNK);
    float s = 0.f;
    for (int c = b0; c < b1; ++c) s += part2[(size_t)c * (NUM_GRAPHS * DIM) + t];
    atomicAdd(&sums[t], s);
}

// out[g] = sigmoid(((sums[g]/max(cnt,1)) @ W2) @ W3)
__global__ void k_final(const float* __restrict__ sums, const int* __restrict__ bound,
                        const float* __restrict__ W2, const float* __restrict__ W3,
                        float* __restrict__ out) {
    int g = threadIdx.x;
    if (g >= NUM_GRAPHS) return;
    float c = fmaxf((float)(bound[g + 1] - bound[g]), 1.f);
    float p[DIM];
#pragma unroll
    for (int k = 0; k < DIM; ++k) p[k] = sums[g * DIM + k] / c;
    float z = 0.f;
#pragma unroll
    for (int j = 0; j < DIM; ++j) {
        float t = 0.f;
#pragma unroll
        for (int k = 0; k < DIM; ++k) t += p[k] * W2[k * DIM + j];
        z += t * W3[j];
    }
    out[g] = 1.f / (1.f + expf(-z));
}

// ---------------------------------------------------------------------------
// Workspace (bytes):
//   h1       [0,         6400000)   100k x 16 f32
//   pk       [6400000,  19200000)   3.2M int (dst-bucketed); r aliases first
//                                   4 MB after spmm1 completes
//   pk2      [19200000, 25600000)   3.2M ushort (src-bucketed)
//   part     [25600000, 33607680)   782 x 2560 f32; part2 (782x640) aliases it
//   bcnt     [33607680, +1600)      <- zeroed
//   bcnt2    [33609280, +1600)      <- zeroed
//   sums     [33610880, +2560)      <- zeroed
//   bstart   [33613440, +1600)
//   b2start  [33615040, +1600)
//   cursor   [33616640, +1600)
//   cursor2  [33618240, +1600)
//   bound    [33619840, +260)
// ---------------------------------------------------------------------------
extern "C" void kernel_launch(void* const* d_in, const int* in_sizes, int n_in,
                              void* d_out, int out_size, void* d_ws, size_t ws_size,
                              hipStream_t stream) {
    const float* feat = (const float*)d_in[0];
    const float* W1   = (const float*)d_in[1];
    const float* W2   = (const float*)d_in[2];
    const float* W3   = (const float*)d_in[3];
    const int*   src  = (const int*)d_in[4];
    const int*   dst  = (const int*)d_in[5];
    const int*   gids = (const int*)d_in[6];
    float*       out  = (float*)d_out;

    char* ws = (char*)d_ws;
    float*          h1      = (float*)(ws);
    int*            pk      = (int*)(ws + 6400000);
    float*          r       = (float*)(ws + 6400000);   // aliases pk (dead after spmm1)
    unsigned short* pk2     = (unsigned short*)(ws + 19200000);
    float*          part    = (float*)(ws + 25600000);
    float*          part2   = (float*)(ws + 25600000);  // aliases part (dead after merge)
    int*            bcnt    = (int*)(ws + 33607680);
    int*            bcnt2   = (int*)(ws + 33609280);
    float*          sums    = (float*)(ws + 33610880);
    int*            bstart  = (int*)(ws + 33613440);
    int*            b2start = (int*)(ws + 33615040);
    int*            cursor  = (int*)(ws + 33616640);
    int*            cursor2 = (int*)(ws + 33618240);
    int*            bound   = (int*)(ws + 33619840);

    hipMemsetAsync(ws + 33607680, 0, 5760, stream);   // bcnt + bcnt2 + sums

    k_gemm_w1<<<(N_NODES * 32 + 255) / 256, 256, 0, stream>>>(feat, W1, h1);
    k_bounds <<<(N_NODES + 255) / 256, 256, 0, stream>>>(gids, bound);
    k_bhist  <<<EBLOCKS, 512, 0, stream>>>(src, dst, bcnt, bcnt2);
    k_bscan  <<<1, 512, 0, stream>>>(bcnt, bcnt2, bstart, b2start, cursor, cursor2);
    k_bplace <<<EBLOCKS, 512, 0, stream>>>(src, dst, bound, cursor, cursor2, pk, pk2);

    k_spmm1     <<<NCHUNK, 512, 0, stream>>>(h1, bstart, pk, part);
    k_merge_relu<<<NB, 256, 0, stream>>>(part, r);
    k_pass2     <<<NCHUNK, 512, 0, stream>>>(r, b2start, pk2, part2);
    k_sums      <<<(NCHUNK + 78) / 79, 640, 0, stream>>>(part2, sums);

    k_final<<<1, 64, 0, stream>>>(sums, bound, W2, W3, out);
}